// Round 9
// baseline (108.058 us; speedup 1.0000x reference)
//
#include <hip/hip_runtime.h>
#include <math.h>

#define N_ROWS 32768
#define DIM 64
#define KCOMP 64
#define KSPLIT 8
#define KLOCAL 8           // KCOMP / KSPLIT
#define THREADS 256        // 4 waves
#define PREP_THREADS 256
#define ROWS_PER_WAVE 64
#define ROWS_PER_BLOCK 256 // 4 waves * 64 rows
#define ROWGROUPS (N_ROWS / ROWS_PER_BLOCK)   // 128

// R23: 32x32x16 MFMA shape. P is UPPER-TRIANGULAR (P[d][e]=0 for d>e).
// Per k, Pt packs 6 nonzero (ET, ds) slots, ET = e-tile of 32, ds = d-step
// of 16. Zero iff ds >= 2*ET+2 -> keep ET0:{ds0,ds1}, ET1:{ds0..ds3}.
//   slot: 0=(ET0,ds0) 1=(ET0,ds1) 2=(ET1,ds0) 3=(ET1,ds1) 4=(ET1,ds2) 5=(ET1,ds3)
// Per k: 6 slots x 2048 B = 12288 B:
//   slot block: [hi: 64 chunks x 16 B, chunk=lane] [lo: same, +1024]
//   chunk(lane): f16 P[d = ds*16 + (lane>>5)*8 + j][e = ET*32 + (lane&31)],
//   j=0..7. (A-operand map of mfma_32x32x16: 32-idx=lane&31, k=(lane>>5)*8+j.)
// Skipping the zero slots is BIT-IDENTICAL: mfma(0-A, B, acc) adds +/-0.
#define PT_K_BYTES 12288

#define LOG2PI_D 1.8378770664093454836

typedef _Float16 f16x8 __attribute__((ext_vector_type(8)));
typedef float f32x4 __attribute__((ext_vector_type(4)));
typedef float f32x16 __attribute__((ext_vector_type(16)));

#define AS1 __attribute__((address_space(1)))
#define AS3 __attribute__((address_space(3)))

// async 16B/lane global->LDS DMA: lds dest wave-uniform; lane i -> base+i*16
__device__ __forceinline__ void async_copy16(const char* g, char* l) {
  __builtin_amdgcn_global_load_lds((const AS1 unsigned int*)g,
                                   (AS3 unsigned int*)l, 16, 0, 0);
}

// ---------------- digamma (double, recurrence + asymptotic) ----------------
__device__ __forceinline__ double digamma_d(double x) {
  double r = 0.0;
  while (x < 6.0) { r -= 1.0 / x; x += 1.0; }
  double inv = 1.0 / x;
  double inv2 = inv * inv;
  double s = log(x) - 0.5 * inv
      - inv2 * (1.0/12.0 - inv2 * (1.0/120.0 - inv2 * (1.0/252.0
      - inv2 * (1.0/240.0 - inv2 * (1.0/132.0)))));
  return r + s;
}

// ------- prep1: one block per k. LDS-staged transpose repack of P into Pt
//         (6 nonzero 32x32x16-slots). Wave 0: muP, log-det, digamma sums,
//         stick-breaking terms. Also zeroes packed/cnt (fused memset). ----
__global__ void prep1_kernel(const float* __restrict__ means,
                             const float* __restrict__ P,
                             const float* __restrict__ wc,
                             const float* __restrict__ dof,
                             const float* __restrict__ mp,
                             char*   __restrict__ Pt,
                             float*  __restrict__ muP,
                             double* __restrict__ t_arr,
                             double* __restrict__ g_arr,
                             double* __restrict__ pc_arr,
                             uint4*  __restrict__ packed4,  // 16384 x 16 B
                             uint4*  __restrict__ cnt4)     // 64 x 16 B
{
  __shared__ float lds[DIM][DIM + 1];
  const int k = blockIdx.x;
  const int t = threadIdx.x;
  const float* Pk = P + k * DIM * DIM;

  // fused memset: zero packed (64 blk x 256 thr x 16 B = 256 KB) + cnt
  const uint4 z4 = {0u, 0u, 0u, 0u};
  packed4[k * PREP_THREADS + t] = z4;
  if (k == 0 && t < 64) cnt4[t] = z4;

  for (int i = t; i < DIM * DIM; i += PREP_THREADS)
    lds[i >> 6][i & 63] = Pk[i];
  __syncthreads();

  char* dst = Pt + (size_t)k * PT_K_BYTES;
#pragma unroll
  for (int cc = 0; cc < 3; ++cc) {                // 768 cids = 6 slots x 2 KB
    int cid  = cc * PREP_THREADS + t;
    int slot = cid >> 7;               // 0..5
    int sel  = (cid >> 6) & 1;         // 0=hi 1=lo
    int lane = cid & 63;
    int ET = slot < 2 ? 0 : 1;
    int ds = slot < 2 ? slot : slot - 2;
    int m32 = lane & 31, h = lane >> 5;
    int e  = ET * 32 + m32;
    int d0 = ds * 16 + h * 8;
    f16x8 o;
#pragma unroll
    for (int j = 0; j < 8; ++j) {
      float v = lds[d0 + j][e];
      _Float16 hh = (_Float16)v;
      o[j] = sel ? (_Float16)(v - (float)hh) : hh;
    }
    *(f16x8*)(dst + cid * 16) = o;
  }

  if (t < 64) {
    const int i = t;
    const float* mk = means + k * DIM;
    float acc = 0.f;
#pragma unroll 8
    for (int d = 0; d < DIM; ++d) acc = fmaf(mk[d], lds[d][i], acc);
    muP[k * DIM + i] = acc;

    double dofk = (double)dof[k];
    double s1 = digamma_d(0.5 * (dofk - (double)i));
    double s2 = log((double)lds[i][i]);
#pragma unroll
    for (int off = 32; off > 0; off >>= 1) {
      s1 += __shfl_down(s1, off);
      s2 += __shfl_down(s2, off);
    }
    if (i == 0) {
      double ak = (double)wc[k], bk = (double)wc[KCOMP + k];
      double dgab = digamma_d(ak + bk);
      double log_lambda = (double)DIM * log(2.0) + s1;
      double pc = s2
                - 0.5 * (double)DIM * LOG2PI_D
                - 0.5 * (double)DIM * log(dofk)
                + 0.5 * (log_lambda - (double)DIM / (double)mp[k]);
      t_arr[k] = digamma_d(bk) - dgab;
      g_arr[k] = digamma_d(ak) - dgab;
      pc_arr[k] = pc;
    }
  }
}

// -------- main: R23 = R22 + 32x32x16 MFMA shape (half the instructions,
//          same FLOPs). Per wave-ki: 36 MFMA (vs 72 of 16x16x32), -17%
//          pipe cycles (4060 vs 3378 FLOP/cyc at ubench rates). A=P, B=X
//          (swapped operands kept): D[e][n] with n=lane&31 (+32*NT), e
//          spread over 16 acc regs + lane-half. Fold: 32 in-reg squares
//          per NT-pair + 2 plain shfl_xor(32) + 1 lane-half select (vs 8
//          shuffles + 6 selects). Triangular skip at (ET,ds): keep 6/8.
//          Sum association over d changes (16-chunks) - same reassoc class
//          as R19 (absmax stayed 0). Base: f16-split products (Phh,Plh,Phl),
//          double-buffered LDS B via async DMA, per-ki barrier, setprio
//          around MFMA phase (R22), fused argmax, NO fences (R8). ---------
__global__ __launch_bounds__(THREADS, 4) void main_kernel(
    const float* __restrict__ X,
    const char*  __restrict__ Pt,
    const float* __restrict__ muP,
    const double* __restrict__ t_arr,
    const double* __restrict__ g_arr,
    const double* __restrict__ pc_arr,
    unsigned long long* __restrict__ packed,  // [N_ROWS], zeroed by prep1
    int* __restrict__ cnt,                    // [ROWGROUPS], zeroed by prep1
    int* __restrict__ out)
{
  __shared__ uint4 bbuf[2][PT_K_BYTES / 16];  // 2 x 12 KB B double-buffer
  __shared__ __align__(16) float mup_lds[KLOCAL * DIM];
  __shared__ float cvec_lds[KCOMP];
  __shared__ int is_last;

  const int tid  = threadIdx.x;
  const int wave = tid >> 6;           // 0..3
  const int lane = tid & 63;
  const int m32  = lane & 31;          // MFMA 32-index (A row = e, B col = n)
  const int h    = lane >> 5;          // K-half selector
  const int ks   = blockIdx.y;
  const int rowbase = blockIdx.x * ROWS_PER_BLOCK + wave * ROWS_PER_WAVE;
  const int k0   = ks * KLOCAL;

  // ---- kick off async stage of k0's B image into buf 0 (3 DMA insts/wave) --
  {
    const char* src = Pt + (size_t)k0 * PT_K_BYTES;
#pragma unroll
    for (int i = 0; i < 3; ++i) {
      const int g = wave * 3 + i;                    // 1 KB group, uniform/wave
      async_copy16(src + (g << 10) + (lane << 4),
                   (char*)&bbuf[0][g << 6]);
    }
  }

  // wave 0: stick-breaking prefix -> cvec in LDS (6 shuffles)
  if (tid < 64) {
    double t = t_arr[tid];
    double s = t;
#pragma unroll
    for (int off = 1; off < 64; off <<= 1) {
      double v = __shfl_up(s, off);
      if (tid >= off) s += v;
    }
    cvec_lds[tid] = (float)(pc_arr[tid] + g_arr[tid] + (s - t));
  }
  // stage this block's muP slice: [k_local][e], coalesced
  for (int i = tid; i < KLOCAL * DIM; i += THREADS)
    mup_lds[i] = muP[ks * KLOCAL * DIM + i];

  // ---- load + split X rows into register fragments [NT][ds] ----
  // B-operand map: lane holds X[n = NT*32 + m32][d = ds*16 + h*8 + j], j=0..7
  f16x8 xhi[2][4], xlo[2][4];
#pragma unroll
  for (int nt = 0; nt < 2; ++nt) {
    int row = rowbase + nt * 32 + m32;
    const float* xp = X + row * DIM;
#pragma unroll
    for (int ds = 0; ds < 4; ++ds) {
      const float4* xq4 = (const float4*)(xp + ds * 16 + h * 8);
      float4 v0 = xq4[0], v1 = xq4[1];
      float xv[8] = {v0.x, v0.y, v0.z, v0.w, v1.x, v1.y, v1.z, v1.w};
      f16x8 hh, ll;
#pragma unroll
      for (int j = 0; j < 8; ++j) {
        _Float16 hv = (_Float16)xv[j];
        hh[j] = hv;
        ll[j] = (_Float16)(xv[j] - (float)hv);
      }
      xhi[nt][ds] = hh;
      xlo[nt][ds] = ll;
    }
  }

  __syncthreads();   // buf0 DMA drained (vmcnt) + cvec/mup visible

  float best = -INFINITY;
  int   bidx = 0;

  for (int ki = 0; ki < KLOCAL; ++ki) {
    const int k = k0 + ki;
    const int p = ki & 1;

    // async stage next k's B into the other buffer (lands during compute)
    if (ki + 1 < KLOCAL) {
      const char* src = Pt + (size_t)(k + 1) * PT_K_BYTES;
#pragma unroll
      for (int i = 0; i < 3; ++i) {
        const int g = wave * 3 + i;
        async_copy16(src + (g << 10) + (lane << 4),
                     (char*)&bbuf[1 - p][g << 6]);
      }
    }

    const char* lb = (const char*)bbuf[p];
    const float ck = cvec_lds[k];
    float sq0 = 0.f, sq1 = 0.f;

    // T5: prioritize this wave while it's in the MFMA-dense phase.
    __builtin_amdgcn_s_setprio(1);
#pragma unroll
    for (int ET = 0; ET < 2; ++ET) {
      // bias: acc reg r holds D[e][n], e = ET*32 + (r&3) + 8*(r>>2) + 4*h.
      // Init acc = -muP[e]: reg r = g*4+i (g=r>>2) <- -mup[ET*32 + 8g + 4h + i]
      f32x16 a0, a1;
#pragma unroll
      for (int g = 0; g < 4; ++g) {
        const f32x4 mv = *(const f32x4*)&mup_lds[(ki << 6) + (ET << 5)
                                                 + (g << 3) + (h << 2)];
#pragma unroll
        for (int i = 0; i < 4; ++i) a0[g * 4 + i] = -mv[i];
      }
      a1 = a0;

#pragma unroll
      for (int ds = 0; ds < 4; ++ds) {
        if (ET == 0 && ds >= 2) continue;     // triangular skip (folds away)
        const int slot = (ET == 0) ? ds : 2 + ds;
        // consecutive lanes -> consecutive 16B: 2-way bank aliasing (free)
        const char* bp = lb + (slot << 11) + (lane << 4);
        f16x8 ph = *(const f16x8*)bp;
        f16x8 pl = *(const f16x8*)(bp + 1024);
        // split products in R19/R22 order: Phi*Xhi, Plo*Xhi, Phi*Xlo
        a0 = __builtin_amdgcn_mfma_f32_32x32x16_f16(ph, xhi[0][ds], a0, 0, 0, 0);
        a0 = __builtin_amdgcn_mfma_f32_32x32x16_f16(pl, xhi[0][ds], a0, 0, 0, 0);
        a0 = __builtin_amdgcn_mfma_f32_32x32x16_f16(ph, xlo[0][ds], a0, 0, 0, 0);
        a1 = __builtin_amdgcn_mfma_f32_32x32x16_f16(ph, xhi[1][ds], a1, 0, 0, 0);
        a1 = __builtin_amdgcn_mfma_f32_32x32x16_f16(pl, xhi[1][ds], a1, 0, 0, 0);
        a1 = __builtin_amdgcn_mfma_f32_32x32x16_f16(ph, xlo[1][ds], a1, 0, 0, 0);
      }

#pragma unroll
      for (int r = 0; r < 16; ++r) {
        sq0 = fmaf(a0[r], a0[r], sq0);
        sq1 = fmaf(a1[r], a1[r], sq1);
      }
    }
    __builtin_amdgcn_s_setprio(0);

    // lanes l and l^32 hold complementary e-halves: one xor-32 add each.
    // lane publishes n = lane: lane<32 -> NT0 row lane; lane>=32 -> NT1.
    float z0 = sq0 + __shfl_xor(sq0, 32);
    float z1 = sq1 + __shfl_xor(sq1, 32);
    float z  = (lane < 32) ? z0 : z1;

    float wv = fmaf(-0.5f, z, ck);
    if (wv > best || (wv == best && k < bidx)) { best = wv; bidx = k; }

    __syncthreads();   // next buffer's DMA drained; all waves done with buf p
  }

  // ---- publish per-row best via one atomicMax(u64), all 64 lanes ----
  // lane's row = rowbase + lane.
  // key: monotone(float) high 32 bits, (63-k) low -> max == argmax with
  // first-max (min-k) tie-break, matching jnp.argmax.
  {
    int row = rowbase + lane;
    unsigned int b = __float_as_uint(best);
    unsigned int u = (b & 0x80000000u) ? ~b : (b | 0x80000000u);
    unsigned long long pkd = ((unsigned long long)u << 32)
                           | (unsigned long long)(63 - bidx);
    atomicMax(&packed[row], pkd);
  }
  __builtin_amdgcn_s_waitcnt(0);   // atomics ack'd at coherent point (local op)
  __syncthreads();
  if (tid == 0) {
    int old = atomicAdd(&cnt[blockIdx.x], 1);
    is_last = (old == KSPLIT - 1);
  }
  __syncthreads();
  if (is_last) {
    int n = blockIdx.x * ROWS_PER_BLOCK + tid;
    unsigned long long pv = __hip_atomic_load(&packed[n], __ATOMIC_RELAXED,
                                              __HIP_MEMORY_SCOPE_AGENT);
    out[n] = 63 - (int)(pv & 63ull);
  }
}

extern "C" void kernel_launch(void* const* d_in, const int* in_sizes, int n_in,
                              void* d_out, int out_size, void* d_ws, size_t ws_size,
                              hipStream_t stream) {
  const float* X     = (const float*)d_in[0];
  const float* means = (const float*)d_in[1];
  const float* P     = (const float*)d_in[2];
  const float* wc    = (const float*)d_in[3];
  const float* dof   = (const float*)d_in[4];
  const float* mp    = (const float*)d_in[5];
  int* out = (int*)d_out;

  // workspace layout (bytes):
  // [0,16384)           muP (4096 f32)
  // [16640,17152)       t_arr (64 f64)
  // [17152,17664)       g_arr
  // [17664,18176)       pc_arr
  // [20480,21504)       cnt (<=256 i32)
  // [24576,286720)      packed (32768 u64)
  // [294912, +786432)   Pt (64 k * 12288 B)
  char* wsb = (char*)d_ws;
  float*  muP    = (float*)(wsb);
  double* t_arr  = (double*)(wsb + 16640);
  double* g_arr  = (double*)(wsb + 17152);
  double* pc_arr = (double*)(wsb + 17664);
  int*    cnt    = (int*)(wsb + 20480);
  unsigned long long* packed = (unsigned long long*)(wsb + 24576);
  char*   Pt     = wsb + 294912;

  prep1_kernel<<<KCOMP, PREP_THREADS, 0, stream>>>(means, P, wc, dof, mp, Pt,
                                                   muP, t_arr, g_arr, pc_arr,
                                                   (uint4*)packed, (uint4*)cnt);

  dim3 grid(ROWGROUPS, KSPLIT);
  main_kernel<<<grid, THREADS, 0, stream>>>(X, Pt, muP, t_arr, g_arr, pc_arr,
                                            packed, cnt, out);
}